// Round 3
// baseline (113.138 us; speedup 1.0000x reference)
//
#include <hip/hip_runtime.h>
#include <math.h>

#define NQ 10
#define NPAR 100
#define FDIM 256
#define BATCH 256
#define NOUT 30
#define TWO_PI_F 6.283185307179586f
#define NSLOT 16

// Round 10: ONE WAVE PER SIM, zero barriers, zero LDS exchanges.
// r7/r8/r9 showed scheduling (occupancy, barrier independence) is not the
// bottleneck: all land at ~25-28us kernel. Remaining suspect: LDS round-trips
// for wave-bit gates + too little ILP (NSLOT=4) to hide cross-lane latency.
// This version: amp index (10 bits): bits[5:0] -> lane (wire w <-> amp bit 9-w,
// wires 9..4), bits[9:6] -> register slots (wires 3,2,1,0). Every gate is
// in-register (pair math) or cross-lane (DPP/swizzle); NO exchange gates.
// Block = 192 threads = 3 waves = 3 branches of one batch item (independent;
// single __syncthreads only before the in-block combine). Grid = 256 ->
// 1 block/CU, 3 waves/CU. Single kernel, no workspace.
// Cross-lane: DPP masks 1,2,8; ds_swizzle 4,16; shfl_xor 32.

template<int MASK>
__device__ __forceinline__ float lx(float v) {
    if constexpr (MASK == 1) {
        return __int_as_float(__builtin_amdgcn_update_dpp(
            0, __float_as_int(v), 0xB1, 0xF, 0xF, true));   // quad_perm [1,0,3,2]
    } else if constexpr (MASK == 2) {
        return __int_as_float(__builtin_amdgcn_update_dpp(
            0, __float_as_int(v), 0x4E, 0xF, 0xF, true));   // quad_perm [2,3,0,1]
    } else if constexpr (MASK == 8) {
        return __int_as_float(__builtin_amdgcn_update_dpp(
            0, __float_as_int(v), 0x128, 0xF, 0xF, true));  // row_ror:8 == xor 8
    } else if constexpr (MASK == 4) {
        return __int_as_float(__builtin_amdgcn_ds_swizzle(__float_as_int(v), 0x101F));
    } else if constexpr (MASK == 16) {
        return __int_as_float(__builtin_amdgcn_ds_swizzle(__float_as_int(v), 0x401F));
    } else {
        return __shfl_xor(v, 32, 64);
    }
}

template<int MASK>
__device__ __forceinline__ float2 lx2(float2 v) {
    return make_float2(lx<MASK>(v.x), lx<MASK>(v.y));
}

__device__ __forceinline__ float2 cmul(float2 a, float2 b) {
    return make_float2(a.x*b.x - a.y*b.y, a.x*b.y + a.y*b.x);
}

// ---- CRX(theta): control amp-bit BC, target amp-bit BT; c=cos(t/2), s=sin(t/2) ----
// Amp bits 0..5 = lane bits; 6..9 = register-slot bits (rb = 1<<(bit-6)).
template<int BC, int BT>
__device__ __forceinline__ void crx(float2 (&st)[NSLOT], int lane, float c, float s)
{
    if constexpr (BT >= 6) {
        constexpr int rt = 1 << (BT - 6);
        if constexpr (BC >= 6) {
            constexpr int rc = 1 << (BC - 6);
            #pragma unroll
            for (int a = 0; a < NSLOT; ++a) {
                if (!(a & rc) || (a & rt)) continue;
                const int a1 = a | rt;
                const float2 A0 = st[a], A1 = st[a1];
                st[a]  = make_float2(c*A0.x + s*A1.y, c*A0.y - s*A1.x);
                st[a1] = make_float2(c*A1.x + s*A0.y, c*A1.y - s*A0.x);
            }
        } else {
            const bool act = (lane >> BC) & 1;
            const float cc = act ? c : 1.f, ss = act ? s : 0.f;
            #pragma unroll
            for (int a = 0; a < NSLOT; ++a) {
                if (a & rt) continue;
                const int a1 = a | rt;
                const float2 A0 = st[a], A1 = st[a1];
                st[a]  = make_float2(cc*A0.x + ss*A1.y, cc*A0.y - ss*A1.x);
                st[a1] = make_float2(cc*A1.x + ss*A0.y, cc*A1.y - ss*A0.x);
            }
        }
    } else {
        constexpr int M = 1 << BT;
        if constexpr (BC >= 6) {
            constexpr int rc = 1 << (BC - 6);
            #pragma unroll
            for (int a = 0; a < NSLOT; ++a) {
                if (!(a & rc)) continue;
                const float2 p = lx2<M>(st[a]); const float2 m = st[a];
                st[a] = make_float2(c*m.x + s*p.y, c*m.y - s*p.x);
            }
        } else {
            const bool act = (lane >> BC) & 1;
            const float cc = act ? c : 1.f, ss = act ? s : 0.f;
            #pragma unroll
            for (int a = 0; a < NSLOT; ++a) {
                const float2 p = lx2<M>(st[a]); const float2 m = st[a];
                st[a] = make_float2(cc*m.x + ss*p.y, cc*m.y - ss*p.x);
            }
        }
    }
}

// ---- fused 1-qubit gate U = Rz*Ry*Rx on amp-bit BIT ----
template<int BIT>
__device__ __forceinline__ void gate1q(float2 (&st)[NSLOT], int lane,
                                       float2 u00, float2 u01, float2 u10, float2 u11)
{
    if constexpr (BIT >= 6) {
        constexpr int rb = 1 << (BIT - 6);
        #pragma unroll
        for (int a = 0; a < NSLOT; ++a) {
            if (a & rb) continue;
            const int a1 = a | rb;
            const float2 A0 = st[a], A1 = st[a1];
            float2 n0, n1;
            n0.x = u00.x*A0.x - u00.y*A0.y + u01.x*A1.x - u01.y*A1.y;
            n0.y = u00.x*A0.y + u00.y*A0.x + u01.x*A1.y + u01.y*A1.x;
            n1.x = u10.x*A0.x - u10.y*A0.y + u11.x*A1.x - u11.y*A1.y;
            n1.y = u10.x*A0.y + u10.y*A0.x + u11.x*A1.y + u11.y*A1.x;
            st[a] = n0; st[a1] = n1;
        }
    } else {
        constexpr int M = 1 << BIT;
        const bool hi = (lane >> BIT) & 1;
        const float2 A = hi ? u11 : u00;
        const float2 B = hi ? u10 : u01;
        #pragma unroll
        for (int a = 0; a < NSLOT; ++a) {
            const float2 p = lx2<M>(st[a]); const float2 m = st[a];
            st[a] = make_float2(A.x*m.x - A.y*m.y + B.x*p.x - B.y*p.y,
                                A.x*m.y + A.y*m.x + B.x*p.y + B.y*p.x);
        }
    }
}

// ---- recursive circuit drivers ----
template<int Q>
__device__ __forceinline__ void layer1q(float2 (&st)[NSLOT], int lane,
                                        const float2* cs, int idx)
{
    if constexpr (Q < NQ) {
        const float2 X = cs[idx], Y = cs[idx + 1], Z = cs[idx + 2];
        const float cx_ = X.x, sx = X.y, cy = Y.x, sy = Y.y, cz = Z.x, sz = Z.y;
        const float2 m00 = make_float2( cy*cx_,  sy*sx);
        const float2 m01 = make_float2(-sy*cx_, -cy*sx);
        const float2 m10 = make_float2( sy*cx_, -cy*sx);
        const float2 m11 = make_float2( cy*cx_, -sy*sx);
        const float2 u00 = make_float2(cz*m00.x + sz*m00.y, cz*m00.y - sz*m00.x);
        const float2 u01 = make_float2(cz*m01.x + sz*m01.y, cz*m01.y - sz*m01.x);
        const float2 u10 = make_float2(cz*m10.x - sz*m10.y, cz*m10.y + sz*m10.x);
        const float2 u11 = make_float2(cz*m11.x - sz*m11.y, cz*m11.y + sz*m11.x);
        gate1q<9 - Q>(st, lane, u00, u01, u10, u11);
        layer1q<Q + 1>(st, lane, cs, idx + 3);
    }
}

template<int Q>
__device__ __forceinline__ void ringF(float2 (&st)[NSLOT], int lane,
                                      const float2* cs, int idx)
{
    if constexpr (Q < NQ) {
        const float2 p = cs[idx];
        crx<9 - Q, 9 - ((Q + 1) % NQ)>(st, lane, p.x, p.y);
        ringF<Q + 1>(st, lane, cs, idx + 1);
    }
}

template<int Q>
__device__ __forceinline__ void ringB(float2 (&st)[NSLOT], int lane,
                                      const float2* cs, int idx)
{
    if constexpr (Q >= 0) {
        const float2 p = cs[idx];
        crx<9 - Q, 9 - ((Q + NQ - 1) % NQ)>(st, lane, p.x, p.y);
        ringB<Q - 1>(st, lane, cs, idx + 1);
    }
}

// ---- column 0 of fused U = Rz*Ry*Rx (product-state init; verified r3-r9) ----
__device__ __forceinline__ void col0(const float2* cs, int w, float2& u00, float2& u10)
{
    const float2 X = cs[3*w], Y = cs[3*w + 1], Z = cs[3*w + 2];
    const float cx = X.x, sx = X.y, cy = Y.x, sy = Y.y, cz = Z.x, sz = Z.y;
    const float2 m00 = make_float2(cy*cx,  sy*sx);
    const float2 m10 = make_float2(sy*cx, -cy*sx);
    u00 = make_float2(cz*m00.x + sz*m00.y, cz*m00.y - sz*m00.x);
    u10 = make_float2(cz*m10.x - sz*m10.y, cz*m10.y + sz*m10.x);
}

// ---- measurements: per-wire partials, full 6-step butterfly (masks 1..32),
//      lane 0 writes the final X/Y/Z sums for its branch ----
template<int Wq>
__device__ __forceinline__ void measureAll(const float2 (&st)[NSLOT], int lane,
                                           float* mrow /* [NOUT] for this branch */)
{
    if constexpr (Wq < NQ) {
        constexpr int B = 9 - Wq;
        float sre = 0.f, smm = 0.f, szz = 0.f;
        if constexpr (B >= 6) {
            constexpr int rb = 1 << (B - 6);
            #pragma unroll
            for (int a = 0; a < NSLOT; ++a) {
                if (a & rb) continue;
                const int a1 = a | rb;
                const float2 A0 = st[a], A1 = st[a1];
                sre += A0.x*A1.x + A0.y*A1.y;
                smm += A0.x*A1.y - A0.y*A1.x;
                szz += A0.x*A0.x + A0.y*A0.y - A1.x*A1.x - A1.y*A1.y;
            }
            sre *= 2.f; smm *= 2.f;
        } else {
            constexpr int M = 1 << B;
            const float sgn = ((lane >> B) & 1) ? -1.f : 1.f;
            #pragma unroll
            for (int a = 0; a < NSLOT; ++a) {
                const float2 m = st[a];
                const float2 p = lx2<M>(m);
                sre += m.x*p.x + m.y*p.y;
                smm += sgn * (m.x*p.y - m.y*p.x);
                szz += sgn * (m.x*m.x + m.y*m.y - p.x*p.x - p.y*p.y);
            }
            szz *= 0.5f;
        }
        sre += lx<1>(sre); sre += lx<2>(sre); sre += lx<4>(sre);
        sre += lx<8>(sre); sre += lx<16>(sre); sre += lx<32>(sre);
        smm += lx<1>(smm); smm += lx<2>(smm); smm += lx<4>(smm);
        smm += lx<8>(smm); smm += lx<16>(smm); smm += lx<32>(smm);
        szz += lx<1>(szz); szz += lx<2>(szz); szz += lx<4>(szz);
        szz += lx<8>(szz); szz += lx<16>(szz); szz += lx<32>(szz);
        if (lane == 0) {
            mrow[Wq]      = sre;
            mrow[10 + Wq] = smm;
            mrow[20 + Wq] = szz;
        }
        measureAll<Wq + 1>(st, lane, mrow);
    }
}

__global__ __launch_bounds__(192) void qsb_fused(
    const float* __restrict__ x,
    const float* __restrict__ W1, const float* __restrict__ b1, const float* __restrict__ base1,
    const float* __restrict__ W2, const float* __restrict__ b2, const float* __restrict__ base2,
    const float* __restrict__ W3, const float* __restrict__ b3, const float* __restrict__ base3,
    const float* __restrict__ ar_, const float* __restrict__ ai_,
    const float* __restrict__ br_, const float* __restrict__ bi_,
    const float* __restrict__ gr_, const float* __restrict__ gi_,
    float* __restrict__ out)
{
    const int b    = blockIdx.x;             // batch item
    const int tid  = threadIdx.x;
    const int br   = tid >> 6;               // branch = wave id
    const int lane = tid & 63;

    const float* Wp   = (br == 0) ? W1    : (br == 1) ? W2    : W3;
    const float* bias = (br == 0) ? b1    : (br == 1) ? b2    : b3;
    const float* base = (br == 0) ? base1 : (br == 1) ? base2 : base3;

    __shared__ float2 css[3][NPAR];
    __shared__ float  mred[3][NOUT];

    // ---- params: p = sigmoid(x.W^T + bias + base) * 2pi ; store (cos,sin)(p/2).
    // Each lane handles params {lane, lane+64}; x row shared between the two.
    {
        const float4* xr = reinterpret_cast<const float4*>(x + (size_t)b * FDIM);
        const float4* w0 = reinterpret_cast<const float4*>(Wp + (size_t)lane * FDIM);
        const int  p1    = lane + 64;
        const bool has1  = (p1 < NPAR);
        const float4* w1 = reinterpret_cast<const float4*>(
            Wp + (size_t)(has1 ? p1 : lane) * FDIM);
        float a00 = 0.f, a01 = 0.f, a02 = 0.f, a03 = 0.f;
        float a10 = 0.f, a11 = 0.f, a12 = 0.f, a13 = 0.f;
        #pragma unroll 8
        for (int k = 0; k < FDIM / 4; ++k) {
            const float4 xv = xr[k];
            const float4 u = w0[k];
            a00 += xv.x*u.x; a01 += xv.y*u.y; a02 += xv.z*u.z; a03 += xv.w*u.w;
            const float4 v = w1[k];
            a10 += xv.x*v.x; a11 += xv.y*v.y; a12 += xv.z*v.z; a13 += xv.w*v.w;
        }
        {
            float acc = (a00 + a01) + (a02 + a03) + bias[lane] + base[lane];
            const float t = TWO_PI_F / (1.f + __expf(-acc));
            float sn, cn;
            __sincosf(0.5f * t, &sn, &cn);
            css[br][lane] = make_float2(cn, sn);
        }
        if (has1) {
            float acc = (a10 + a11) + (a12 + a13) + bias[p1] + base[p1];
            const float t = TWO_PI_F / (1.f + __expf(-acc));
            float sn, cn;
            __sincosf(0.5f * t, &sn, &cn);
            css[br][p1] = make_float2(cn, sn);
        }
    }
    // No barrier: css[br] is written and read by the same single wave only;
    // the wave's own lgkmcnt ordering (compiler-inserted) covers the RAW.

    const float2* cs = css[br];

    // ---- sweep 1 folded into product-state init ----
    float2 st[NSLOT];
    {
        float2 lp = make_float2(1.f, 0.f);
        #pragma unroll
        for (int bb = 0; bb < 6; ++bb) {            // lane bit bb <-> wire 9-bb
            float2 u00, u10;
            col0(cs, 9 - bb, u00, u10);
            lp = cmul(lp, ((lane >> bb) & 1) ? u10 : u00);
        }
        float2 f3[2], f2[2], f1[2], f0[2];          // slot bits 0..3 <-> wires 3,2,1,0
        col0(cs, 3, f3[0], f3[1]);
        col0(cs, 2, f2[0], f2[1]);
        col0(cs, 1, f1[0], f1[1]);
        col0(cs, 0, f0[0], f0[1]);
        float2 g[4], h[4];
        g[0] = cmul(f3[0], f2[0]); g[1] = cmul(f3[1], f2[0]);
        g[2] = cmul(f3[0], f2[1]); g[3] = cmul(f3[1], f2[1]);
        h[0] = cmul(f1[0], f0[0]); h[1] = cmul(f1[1], f0[0]);
        h[2] = cmul(f1[0], f0[1]); h[3] = cmul(f1[1], f0[1]);
        #pragma unroll
        for (int a = 0; a < NSLOT; ++a)
            st[a] = cmul(cmul(g[a & 3], h[(a >> 2) & 3]), lp);
    }

    // ---- circuit (sweep 1 already folded) ----
    ringF<0>(st, lane, cs, 30);
    ringB<NQ - 1>(st, lane, cs, 40);
    layer1q<0>(st, lane, cs, 50);
    ringF<0>(st, lane, cs, 80);
    ringB<NQ - 1>(st, lane, cs, 90);

    // ---- measurements (per-branch, fully in-wave) ----
    measureAll<0>(st, lane, &mred[br][0]);
    __syncthreads();                          // the ONLY block-wide barrier

    // ---- combine: out = |alpha*m1 + beta*m2 + gamma*m3| / norm ----
    if (tid < NOUT) {
        const int j = tid;
        const float m1 = mred[0][j];
        const float m2 = mred[1][j];
        const float m3 = mred[2][j];
        const float ar = ar_[0], ai = ai_[0];
        const float brr = br_[0], bii = bi_[0];
        const float gr = gr_[0], gi = gi_[0];
        const float inv = 1.f / sqrtf(ar*ar + ai*ai + brr*brr + bii*bii
                                      + gr*gr + gi*gi + 1e-9f);
        const float re = (ar * m1 + brr * m2 + gr * m3) * inv;
        const float im = (ai * m1 + bii * m2 + gi * m3) * inv;
        out[(size_t)b * NOUT + j] = sqrtf(re * re + im * im);
    }
}

extern "C" void kernel_launch(void* const* d_in, const int* in_sizes, int n_in,
                              void* d_out, int out_size, void* d_ws, size_t ws_size,
                              hipStream_t stream)
{
    (void)in_sizes; (void)n_in; (void)out_size; (void)d_ws; (void)ws_size;
    const float* x     = (const float*)d_in[0];
    const float* W1    = (const float*)d_in[1];
    const float* b1    = (const float*)d_in[2];
    const float* W2    = (const float*)d_in[3];
    const float* b2    = (const float*)d_in[4];
    const float* W3    = (const float*)d_in[5];
    const float* b3    = (const float*)d_in[6];
    const float* base1 = (const float*)d_in[7];
    const float* base2 = (const float*)d_in[8];
    const float* base3 = (const float*)d_in[9];
    const float* ar    = (const float*)d_in[10];
    const float* ai    = (const float*)d_in[11];
    const float* br    = (const float*)d_in[12];
    const float* bi    = (const float*)d_in[13];
    const float* gr    = (const float*)d_in[14];
    const float* gi    = (const float*)d_in[15];

    qsb_fused<<<dim3(BATCH), dim3(192), 0, stream>>>(
        x, W1, b1, base1, W2, b2, base2, W3, b3, base3,
        ar, ai, br, bi, gr, gi, (float*)d_out);
}

// Round 4
// 106.833 us; speedup vs baseline: 1.0590x; 1.0590x over previous
//
#include <hip/hip_runtime.h>
#include <math.h>

#define NQ 10
#define NPAR 100
#define FDIM 256
#define BATCH 256
#define NOUT 30
#define TWO_PI_F 6.283185307179586f
#define NSLOT 4

// Round 11: r8 structure (best: 3 branches x 4 waves, NSLOT=4, double-buffered
// single-barrier exchanges, block 768, grid 256) with ALL complex arithmetic
// rewritten as ext_vector float2 so the backend emits packed VOP3P f32 ops
// (v_pk_fma_f32/v_pk_mul_f32, swap+neg folded into op_sel/neg modifiers).
// Rationale: r7-r10 showed kernel time (~27-33us) is invariant to occupancy,
// barriers, and exchange count -> bottleneck is the per-wave scalar VALU
// stream itself (2 instr per complex component-pair, 20-45KB unrolled code).
// Packed math halves instruction count and code size.
// Complex identities used (verified vs scalar forms):
//   cmul(a,b)    = {a.x,a.x}*b + {-a.y,a.y}*{b.y,b.x}
//   RX half step = c*m + s*{p.y,-p.x}
//   U = Rz*Ry*Rx: u0k = cmul({cz,-sz}, m0k), u1k = cmul({cz,sz}, m1k)

typedef float f2 __attribute__((ext_vector_type(2)));

__device__ __forceinline__ f2 spl(float v) { return (f2){v, v}; }
__device__ __forceinline__ f2 csw(f2 v)  { return (f2){v.y, v.x}; }    // swap
__device__ __forceinline__ f2 crot(f2 v) { return (f2){v.y, -v.x}; }   // RX partner
__device__ __forceinline__ f2 cmul(f2 a, f2 b) {
    return spl(a.x) * b + (f2){-a.y, a.y} * csw(b);
}
__device__ __forceinline__ f2 cmac(f2 d, f2 a, f2 b) {                 // d + a*b
    return d + spl(a.x) * b + (f2){-a.y, a.y} * csw(b);
}

template<int MASK>
__device__ __forceinline__ float lx(float v) {
    if constexpr (MASK == 1) {
        return __int_as_float(__builtin_amdgcn_update_dpp(
            0, __float_as_int(v), 0xB1, 0xF, 0xF, true));   // quad_perm [1,0,3,2]
    } else if constexpr (MASK == 2) {
        return __int_as_float(__builtin_amdgcn_update_dpp(
            0, __float_as_int(v), 0x4E, 0xF, 0xF, true));   // quad_perm [2,3,0,1]
    } else if constexpr (MASK == 8) {
        return __int_as_float(__builtin_amdgcn_update_dpp(
            0, __float_as_int(v), 0x128, 0xF, 0xF, true));  // row_ror:8 == xor 8
    } else if constexpr (MASK == 4) {
        return __int_as_float(__builtin_amdgcn_ds_swizzle(__float_as_int(v), 0x101F));
    } else if constexpr (MASK == 16) {
        return __int_as_float(__builtin_amdgcn_ds_swizzle(__float_as_int(v), 0x401F));
    } else {
        return __shfl_xor(v, 32, 64);
    }
}

template<int MASK>
__device__ __forceinline__ f2 lx2(f2 v) {
    return (f2){lx<MASK>(v.x), lx<MASK>(v.y)};
}

struct Ctx {
    int lane;                  // 0..63
    int W;                     // 0..3 wave id within branch
    int ebuf;                  // double-buffer index, toggled per exchange
    f2 (*ex)[4][NSLOT][64];    // [buf][wave][slot][lane]
};

// ---- CRX(theta): control amp-bit BC, target amp-bit BT; c=cos(t/2), s=sin(t/2) ----
template<int BC, int BT>
__device__ __forceinline__ void crx(f2 (&st)[NSLOT], Ctx& cx, float c, float s)
{
    if constexpr (BT >= 8) {
        // target = wave bit: LDS exchange with partner wave over bit (BT-8)
        constexpr int tb = BT - 8;
        const int PW = cx.W ^ (1 << tb);
        if constexpr (BC >= 8) {
            const bool ctrl = (cx.W >> (BC - 8)) & 1;
            if (ctrl) {
                #pragma unroll
                for (int a = 0; a < NSLOT; ++a) cx.ex[cx.ebuf][cx.W][a][cx.lane] = st[a];
            }
            __syncthreads();
            if (ctrl) {
                #pragma unroll
                for (int a = 0; a < NSLOT; ++a) {
                    const f2 p = cx.ex[cx.ebuf][PW][a][cx.lane];
                    st[a] = c * st[a] + s * crot(p);
                }
            }
            cx.ebuf ^= 1;
        } else if constexpr (BC >= 6) {
            constexpr int rc = 1 << (BC - 6);
            #pragma unroll
            for (int a = 0; a < NSLOT; ++a) if (a & rc) cx.ex[cx.ebuf][cx.W][a][cx.lane] = st[a];
            __syncthreads();
            #pragma unroll
            for (int a = 0; a < NSLOT; ++a) if (a & rc) {
                const f2 p = cx.ex[cx.ebuf][PW][a][cx.lane];
                st[a] = c * st[a] + s * crot(p);
            }
            cx.ebuf ^= 1;
        } else {
            #pragma unroll
            for (int a = 0; a < NSLOT; ++a) cx.ex[cx.ebuf][cx.W][a][cx.lane] = st[a];
            __syncthreads();
            const bool act = (cx.lane >> BC) & 1;
            const float cc = act ? c : 1.f, ss = act ? s : 0.f;
            #pragma unroll
            for (int a = 0; a < NSLOT; ++a) {
                const f2 p = cx.ex[cx.ebuf][PW][a][cx.lane];
                st[a] = cc * st[a] + ss * crot(p);
            }
            cx.ebuf ^= 1;
        }
    } else if constexpr (BC >= 8) {
        // control = wave bit (wave-uniform): active waves apply plain RX on target
        const bool ctrl = (cx.W >> (BC - 8)) & 1;
        if (ctrl) {
            if constexpr (BT >= 6) {
                constexpr int rt = 1 << (BT - 6);
                #pragma unroll
                for (int a = 0; a < NSLOT; ++a) {
                    if (a & rt) continue;
                    const int a1 = a | rt;
                    const f2 A0 = st[a], A1 = st[a1];
                    st[a]  = c * A0 + s * crot(A1);
                    st[a1] = c * A1 + s * crot(A0);
                }
            } else {
                constexpr int M = 1 << BT;
                #pragma unroll
                for (int a = 0; a < NSLOT; ++a) {
                    const f2 p = lx2<M>(st[a]);
                    st[a] = c * st[a] + s * crot(p);
                }
            }
        }
    } else if constexpr (BT >= 6) {
        constexpr int rt = 1 << (BT - 6);
        if constexpr (BC >= 6) {
            constexpr int rc = 1 << (BC - 6);
            #pragma unroll
            for (int a = 0; a < NSLOT; ++a) {
                if (!(a & rc) || (a & rt)) continue;
                const int a1 = a | rt;
                const f2 A0 = st[a], A1 = st[a1];
                st[a]  = c * A0 + s * crot(A1);
                st[a1] = c * A1 + s * crot(A0);
            }
        } else {
            const bool act = (cx.lane >> BC) & 1;
            const float cc = act ? c : 1.f, ss = act ? s : 0.f;
            #pragma unroll
            for (int a = 0; a < NSLOT; ++a) {
                if (a & rt) continue;
                const int a1 = a | rt;
                const f2 A0 = st[a], A1 = st[a1];
                st[a]  = cc * A0 + ss * crot(A1);
                st[a1] = cc * A1 + ss * crot(A0);
            }
        }
    } else {
        constexpr int M = 1 << BT;
        if constexpr (BC >= 6) {
            constexpr int rc = 1 << (BC - 6);
            #pragma unroll
            for (int a = 0; a < NSLOT; ++a) {
                if (!(a & rc)) continue;
                const f2 p = lx2<M>(st[a]);
                st[a] = c * st[a] + s * crot(p);
            }
        } else {
            const bool act = (cx.lane >> BC) & 1;
            const float cc = act ? c : 1.f, ss = act ? s : 0.f;
            #pragma unroll
            for (int a = 0; a < NSLOT; ++a) {
                const f2 p = lx2<M>(st[a]);
                st[a] = cc * st[a] + ss * crot(p);
            }
        }
    }
}

// ---- fused 1-qubit gate U = Rz*Ry*Rx on amp-bit BIT ----
template<int BIT>
__device__ __forceinline__ void gate1q(f2 (&st)[NSLOT], Ctx& cx,
                                       f2 u00, f2 u01, f2 u10, f2 u11)
{
    if constexpr (BIT >= 8) {
        constexpr int tb = BIT - 8;
        const int PW = cx.W ^ (1 << tb);
        #pragma unroll
        for (int a = 0; a < NSLOT; ++a) cx.ex[cx.ebuf][cx.W][a][cx.lane] = st[a];
        __syncthreads();
        const bool hi = (cx.W >> tb) & 1;
        const f2 A = hi ? u11 : u00;
        const f2 B = hi ? u10 : u01;
        #pragma unroll
        for (int a = 0; a < NSLOT; ++a) {
            const f2 p = cx.ex[cx.ebuf][PW][a][cx.lane];
            st[a] = cmac(cmul(A, st[a]), B, p);
        }
        cx.ebuf ^= 1;
    } else if constexpr (BIT >= 6) {
        constexpr int rb = 1 << (BIT - 6);
        #pragma unroll
        for (int a = 0; a < NSLOT; ++a) {
            if (a & rb) continue;
            const int a1 = a | rb;
            const f2 A0 = st[a], A1 = st[a1];
            st[a]  = cmac(cmul(u00, A0), u01, A1);
            st[a1] = cmac(cmul(u10, A0), u11, A1);
        }
    } else {
        constexpr int M = 1 << BIT;
        const bool hi = (cx.lane >> BIT) & 1;
        const f2 A = hi ? u11 : u00;
        const f2 B = hi ? u10 : u01;
        #pragma unroll
        for (int a = 0; a < NSLOT; ++a) {
            const f2 p = lx2<M>(st[a]);
            st[a] = cmac(cmul(A, st[a]), B, p);
        }
    }
}

// ---- recursive circuit drivers ----
template<int Q>
__device__ __forceinline__ void layer1q(f2 (&st)[NSLOT], Ctx& cx,
                                        const f2* cs, int idx)
{
    if constexpr (Q < NQ) {
        const f2 X = cs[idx], Y = cs[idx + 1], Z = cs[idx + 2];
        const float cx_ = X.x, sx = X.y, cy = Y.x, sy = Y.y;
        const f2 e0 = (f2){Z.x, -Z.y};                // e^{-iz/2}
        const f2 e1 = (f2){Z.x,  Z.y};                // e^{+iz/2}
        const f2 m00 = (f2){ cy*cx_,  sy*sx};
        const f2 m01 = (f2){-sy*cx_, -cy*sx};
        const f2 m10 = (f2){ sy*cx_, -cy*sx};
        const f2 m11 = (f2){ cy*cx_, -sy*sx};
        const f2 u00 = cmul(e0, m00);
        const f2 u01 = cmul(e0, m01);
        const f2 u10 = cmul(e1, m10);
        const f2 u11 = cmul(e1, m11);
        gate1q<9 - Q>(st, cx, u00, u01, u10, u11);
        layer1q<Q + 1>(st, cx, cs, idx + 3);
    }
}

template<int Q>
__device__ __forceinline__ void ringF(f2 (&st)[NSLOT], Ctx& cx,
                                      const f2* cs, int idx)
{
    if constexpr (Q < NQ) {
        const f2 p = cs[idx];
        crx<9 - Q, 9 - ((Q + 1) % NQ)>(st, cx, p.x, p.y);
        ringF<Q + 1>(st, cx, cs, idx + 1);
    }
}

template<int Q>
__device__ __forceinline__ void ringB(f2 (&st)[NSLOT], Ctx& cx,
                                      const f2* cs, int idx)
{
    if constexpr (Q >= 0) {
        const f2 p = cs[idx];
        crx<9 - Q, 9 - ((Q + NQ - 1) % NQ)>(st, cx, p.x, p.y);
        ringB<Q - 1>(st, cx, cs, idx + 1);
    }
}

// ---- column 0 of fused U = Rz*Ry*Rx (product-state init; verified r3-r10) ----
__device__ __forceinline__ void col0(const f2* cs, int w, f2& u00, f2& u10)
{
    const f2 X = cs[3*w], Y = cs[3*w + 1], Z = cs[3*w + 2];
    const float cx = X.x, sx = X.y, cy = Y.x, sy = Y.y;
    const f2 m00 = (f2){cy*cx,  sy*sx};
    const f2 m10 = (f2){sy*cx, -cy*sx};
    u00 = cmul((f2){Z.x, -Z.y}, m00);
    u10 = cmul((f2){Z.x,  Z.y}, m10);
}

// ---- measurements: per-wire partials, 5-step butterfly (masks 1..16),
//      lanes 0 and 32 of each wave write 8 partials per value ----
template<int Wq>
__device__ __forceinline__ void measureAll(const f2 (&st)[NSLOT], Ctx& cx,
                                           float* mrow /* [8][NOUT] */)
{
    if constexpr (Wq < NQ) {
        constexpr int B = 9 - Wq;
        float sre = 0.f, smm = 0.f, szz = 0.f;
        if constexpr (B >= 8) {
            constexpr int tb = B - 8;
            const int PW = cx.W ^ (1 << tb);
            #pragma unroll
            for (int a = 0; a < NSLOT; ++a) cx.ex[cx.ebuf][cx.W][a][cx.lane] = st[a];
            __syncthreads();
            const float sgn = ((cx.W >> tb) & 1) ? -1.f : 1.f;
            #pragma unroll
            for (int a = 0; a < NSLOT; ++a) {
                const f2 m = st[a];
                const f2 p = cx.ex[cx.ebuf][PW][a][cx.lane];
                sre += m.x*p.x + m.y*p.y;                 // sum over all = 2 Re z01
                smm += sgn * (m.x*p.y - m.y*p.x);         // sum over all = 2 Im z01
                szz += sgn * (m.x*m.x + m.y*m.y);         // sum = Z
            }
            cx.ebuf ^= 1;
        } else if constexpr (B >= 6) {
            constexpr int rb = 1 << (B - 6);
            #pragma unroll
            for (int a = 0; a < NSLOT; ++a) {
                if (a & rb) continue;
                const int a1 = a | rb;
                const f2 A0 = st[a], A1 = st[a1];
                sre += A0.x*A1.x + A0.y*A1.y;
                smm += A0.x*A1.y - A0.y*A1.x;
                szz += A0.x*A0.x + A0.y*A0.y - A1.x*A1.x - A1.y*A1.y;
            }
            sre *= 2.f; smm *= 2.f;
        } else {
            constexpr int M = 1 << B;
            const float sgn = ((cx.lane >> B) & 1) ? -1.f : 1.f;
            #pragma unroll
            for (int a = 0; a < NSLOT; ++a) {
                const f2 m = st[a];
                const f2 p = lx2<M>(m);
                sre += m.x*p.x + m.y*p.y;
                smm += sgn * (m.x*p.y - m.y*p.x);
                szz += sgn * (m.x*m.x + m.y*m.y - p.x*p.x - p.y*p.y);
            }
            szz *= 0.5f;
        }
        sre += lx<1>(sre); sre += lx<2>(sre); sre += lx<4>(sre); sre += lx<8>(sre); sre += lx<16>(sre);
        smm += lx<1>(smm); smm += lx<2>(smm); smm += lx<4>(smm); smm += lx<8>(smm); smm += lx<16>(smm);
        szz += lx<1>(szz); szz += lx<2>(szz); szz += lx<4>(szz); szz += lx<8>(szz); szz += lx<16>(szz);
        if ((cx.lane & 31) == 0) {
            const int k = (cx.W << 1) | (cx.lane >> 5);   // 8 partials per value
            mrow[k * NOUT + Wq]      = sre;
            mrow[k * NOUT + 10 + Wq] = smm;
            mrow[k * NOUT + 20 + Wq] = szz;
        }
        measureAll<Wq + 1>(st, cx, mrow);
    }
}

__global__ __launch_bounds__(768) void qsb_fused(
    const float* __restrict__ x,
    const float* __restrict__ W1, const float* __restrict__ b1, const float* __restrict__ base1,
    const float* __restrict__ W2, const float* __restrict__ b2, const float* __restrict__ base2,
    const float* __restrict__ W3, const float* __restrict__ b3, const float* __restrict__ base3,
    const float* __restrict__ ar_, const float* __restrict__ ai_,
    const float* __restrict__ br_, const float* __restrict__ bi_,
    const float* __restrict__ gr_, const float* __restrict__ gi_,
    float* __restrict__ out)
{
    const int tid  = threadIdx.x;
    const int b    = blockIdx.x;             // batch item
    const int wv   = tid >> 6;               // 0..11
    const int br   = wv >> 2;                // branch
    const int W    = wv & 3;                 // wave id (amp bits 9:8 = wires 0,1)
    const int lane = tid & 63;
    const int lt   = (W << 6) | lane;        // branch-local thread 0..255

    const float* Wp   = (br == 0) ? W1    : (br == 1) ? W2    : W3;
    const float* bias = (br == 0) ? b1    : (br == 1) ? b2    : b3;
    const float* base = (br == 0) ? base1 : (br == 1) ? base2 : base3;

    __shared__ f2    css[3][NPAR];
    __shared__ f2    exb[3][2][4][NSLOT][64];   // [branch][buf][wave][slot][lane]
    __shared__ float mred[3][8][NOUT];

    // ---- params: p = sigmoid(x.W^T + bias + base) * 2pi ; store (cos,sin)(p/2) ----
    if (lt < NPAR) {
        const float4* xr = reinterpret_cast<const float4*>(x + (size_t)b * FDIM);
        const float4* wr = reinterpret_cast<const float4*>(Wp + (size_t)lt * FDIM);
        float a0 = 0.f, a1 = 0.f, a2 = 0.f, a3 = 0.f;   // 4 chains (64-deep each)
        #pragma unroll 8
        for (int k = 0; k < FDIM / 4; ++k) {
            const float4 xv = xr[k];
            const float4 wv4 = wr[k];
            a0 += xv.x*wv4.x; a1 += xv.y*wv4.y; a2 += xv.z*wv4.z; a3 += xv.w*wv4.w;
        }
        float acc = (a0 + a1) + (a2 + a3);
        acc += bias[lt] + base[lt];
        const float t = TWO_PI_F / (1.f + __expf(-acc));
        float sn, cn;
        __sincosf(0.5f * t, &sn, &cn);
        css[br][lt] = (f2){cn, sn};
    }
    __syncthreads();

    const f2* cs = css[br];
    Ctx cx;
    cx.lane = lane; cx.W = W; cx.ebuf = 0;
    cx.ex = exb[br];

    // ---- sweep 1 folded into product-state init ----
    f2 st[NSLOT];
    {
        f2 lp = (f2){1.f, 0.f};
        #pragma unroll
        for (int bbit = 0; bbit < 6; ++bbit) {      // lane bit bbit <-> wire 9-bbit
            f2 u00, u10;
            col0(cs, 9 - bbit, u00, u10);
            lp = cmul(lp, ((lane >> bbit) & 1) ? u10 : u00);
        }
        {                                           // W bit 0 <-> wire 1
            f2 u00, u10;
            col0(cs, 1, u00, u10);
            lp = cmul(lp, (W & 1) ? u10 : u00);
        }
        {                                           // W bit 1 <-> wire 0
            f2 u00, u10;
            col0(cs, 0, u00, u10);
            lp = cmul(lp, ((W >> 1) & 1) ? u10 : u00);
        }
        f2 f3[2], f2v[2];                           // amp bits 6,7 <-> wires 3,2
        col0(cs, 3, f3[0], f3[1]);
        col0(cs, 2, f2v[0], f2v[1]);
        #pragma unroll
        for (int a = 0; a < NSLOT; ++a)
            st[a] = cmul(cmul(f3[a & 1], f2v[(a >> 1) & 1]), lp);
    }

    // ---- circuit (sweep 1 already folded) ----
    ringF<0>(st, cx, cs, 30);
    ringB<NQ - 1>(st, cx, cs, 40);
    layer1q<0>(st, cx, cs, 50);
    ringF<0>(st, cx, cs, 80);
    ringB<NQ - 1>(st, cx, cs, 90);

    // ---- measurements ----
    measureAll<0>(st, cx, &mred[br][0][0]);
    __syncthreads();

    // ---- combine: out = |alpha*m1 + beta*m2 + gamma*m3| / norm ----
    if (tid < NOUT) {
        const int j = tid;
        float m1 = 0.f, m2 = 0.f, m3 = 0.f;
        #pragma unroll
        for (int k = 0; k < 8; ++k) {
            m1 += mred[0][k][j];
            m2 += mred[1][k][j];
            m3 += mred[2][k][j];
        }
        const float ar = ar_[0], ai = ai_[0];
        const float brr = br_[0], bii = bi_[0];
        const float gr = gr_[0], gi = gi_[0];
        const float inv = 1.f / sqrtf(ar*ar + ai*ai + brr*brr + bii*bii
                                      + gr*gr + gi*gi + 1e-9f);
        const float re = (ar * m1 + brr * m2 + gr * m3) * inv;
        const float im = (ai * m1 + bii * m2 + gi * m3) * inv;
        out[(size_t)b * NOUT + j] = sqrtf(re * re + im * im);
    }
}

extern "C" void kernel_launch(void* const* d_in, const int* in_sizes, int n_in,
                              void* d_out, int out_size, void* d_ws, size_t ws_size,
                              hipStream_t stream)
{
    (void)in_sizes; (void)n_in; (void)out_size; (void)d_ws; (void)ws_size;
    const float* x     = (const float*)d_in[0];
    const float* W1    = (const float*)d_in[1];
    const float* b1    = (const float*)d_in[2];
    const float* W2    = (const float*)d_in[3];
    const float* b2    = (const float*)d_in[4];
    const float* W3    = (const float*)d_in[5];
    const float* b3    = (const float*)d_in[6];
    const float* base1 = (const float*)d_in[7];
    const float* base2 = (const float*)d_in[8];
    const float* base3 = (const float*)d_in[9];
    const float* ar    = (const float*)d_in[10];
    const float* ai    = (const float*)d_in[11];
    const float* br    = (const float*)d_in[12];
    const float* bi    = (const float*)d_in[13];
    const float* gr    = (const float*)d_in[14];
    const float* gi    = (const float*)d_in[15];

    qsb_fused<<<dim3(BATCH), dim3(768), 0, stream>>>(
        x, W1, b1, base1, W2, b2, base2, W3, b3, base3,
        ar, ai, br, bi, gr, gi, (float*)d_out);
}